// Round 4
// baseline (235.677 us; speedup 1.0000x reference)
//
#include <hip/hip_runtime.h>

#define CUTN 128
#define CUT_SIZE 224
#define IMG_H 1024
#define IMG_W 1024
#define PAD 256          // IMG_H / 4
#define SIDE 1536        // IMG_H + 2*PAD
#define PX_PER_CUT (CUT_SIZE * CUT_SIZE)   // 50176
#define HALF_PX (PX_PER_CUT / 2)           // 25088
#define BLOCKS_PER_CUT (HALF_PX / 256)     // 98

// Direct-gather kernel, 2 output pixels per thread, branchless x-edges,
// on-device dedupe of identical cutouts (canonical block multi-writes).
__global__ __launch_bounds__(256) void make_cutouts_kernel(
    const float* __restrict__ img,      // (3, 1024, 1024)
    const int* __restrict__ sizes_y,
    const int* __restrict__ sizes_x,
    const int* __restrict__ offs_y,
    const int* __restrict__ offs_x,
    float* __restrict__ out)            // (128, 3, 224, 224)
{
    const int bid = blockIdx.x;
    const int cut = bid / BLOCKS_PER_CUT;            // uniform per block
    const int blk = bid - cut * BLOCKS_PER_CUT;

    const int sy = sizes_y[cut], sx = sizes_x[cut];
    const int oy = offs_y[cut],  ox = offs_x[cut];

    // ---- dedupe scan (block-uniform, scalar) ----
    unsigned long long mlo = 0ull, mhi = 0ull;
    for (int d = 0; d < CUTN; ++d) {
        const bool m = (sizes_y[d] == sy) & (sizes_x[d] == sx) &
                       (offs_y[d]  == oy) & (offs_x[d]  == ox);
        if (m) {
            if (d < cut) return;         // earlier identical cutout owns this work
            if (d < 64) mlo |= (1ull << d);
            else        mhi |= (1ull << (d - 64));
        }
    }

    const float syf = (float)sy, sxf = (float)sx;
    const float oyf = (float)oy, oxf = (float)ox;

    const int t0 = blk * 256 + (int)threadIdx.x;     // 0..25087

    float vout[2][3];
    int   pix[2];

    #pragma unroll
    for (int h = 0; h < 2; ++h) {
        const int p = t0 + h * HALF_PX;
        const int y = p / CUT_SIZE;
        const int x = p - y * CUT_SIZE;
        pix[h] = p;

        // vertical tap (shared by 3 channels)
        const float gy = ((float)y + 0.5f) / (float)CUT_SIZE;
        const float yv = fminf(fmaxf(oyf + gy * syf - 0.5f, 0.0f), (float)(SIDE - 1));
        const int   y0 = (int)floorf(yv);
        const float wy = yv - (float)y0;
        const int  yy0 = y0 - PAD;
        const int  yy1 = min(y0 + 1, SIDE - 1) - PAD;
        const bool vy0 = (unsigned)yy0 < (unsigned)IMG_H;
        const bool vy1 = (unsigned)yy1 < (unsigned)IMG_H;
        const int   r0 = min(max(yy0, 0), IMG_H - 1);
        const int   r1 = min(max(yy1, 0), IMG_H - 1);

        // horizontal tap
        const float gx = ((float)x + 0.5f) / (float)CUT_SIZE;
        const float xv = fminf(fmaxf(oxf + gx * sxf - 0.5f, 0.0f), (float)(SIDE - 1));
        const int   x0 = (int)floorf(xv);
        const float wx = xv - (float)x0;
        const int  xx0 = x0 - PAD;
        const int  xx1 = min(x0 + 1, SIDE - 1) - PAD;
        const bool vx0 = (unsigned)xx0 < (unsigned)IMG_W;
        const bool vx1 = (unsigned)xx1 < (unsigned)IMG_W;
        const int   ax = min(max(xx0, 0), IMG_W - 2);   // clamped pair base
        const bool  s0 = (xx0 != ax);   // p00 taken from .y instead of .x
        const bool  s1 = (xx1 == ax);   // p01 taken from .x instead of .y

        const float w00 = (1.0f - wy) * (1.0f - wx);
        const float w01 = (1.0f - wy) * wx;
        const float w10 = wy * (1.0f - wx);
        const float w11 = wy * wx;

        const size_t o0 = (size_t)r0 * IMG_W + ax;
        const size_t o1 = (size_t)r1 * IMG_W + ax;

        #pragma unroll
        for (int c = 0; c < 3; ++c) {
            const float* plane = img + (size_t)c * (IMG_H * IMG_W);
            float2 a, b;
            __builtin_memcpy(&a, plane + o0, 8);        // row tap 0, pair
            __builtin_memcpy(&b, plane + o1, 8);        // row tap 1, pair

            const float p00 = (vy0 && vx0) ? (s0 ? a.y : a.x) : 0.0f;
            const float p01 = (vy0 && vx1) ? (s1 ? a.x : a.y) : 0.0f;
            const float p10 = (vy1 && vx0) ? (s0 ? b.y : b.x) : 0.0f;
            const float p11 = (vy1 && vx1) ? (s1 ? b.x : b.y) : 0.0f;

            vout[h][c] = p00 * w00 + p01 * w01 + p10 * w10 + p11 * w11;
        }
    }

    // ---- stores: write this cutout and every duplicate (uniform bit loops) ----
    unsigned long long lo = mlo, hi = mhi;
    while (lo) {
        const int d = __ffsll(lo) - 1; lo &= lo - 1;
        #pragma unroll
        for (int h = 0; h < 2; ++h)
            #pragma unroll
            for (int c = 0; c < 3; ++c)
                __builtin_nontemporal_store(
                    vout[h][c],
                    &out[((size_t)d * 3 + c) * PX_PER_CUT + pix[h]]);
    }
    while (hi) {
        const int d = __ffsll(hi) + 63; hi &= hi - 1;
        #pragma unroll
        for (int h = 0; h < 2; ++h)
            #pragma unroll
            for (int c = 0; c < 3; ++c)
                __builtin_nontemporal_store(
                    vout[h][c],
                    &out[((size_t)d * 3 + c) * PX_PER_CUT + pix[h]]);
    }
}

extern "C" void kernel_launch(void* const* d_in, const int* in_sizes, int n_in,
                              void* d_out, int out_size, void* d_ws, size_t ws_size,
                              hipStream_t stream) {
    const float* img     = (const float*)d_in[0];
    const int*   sizes_y = (const int*)d_in[1];
    const int*   sizes_x = (const int*)d_in[2];
    const int*   offs_y  = (const int*)d_in[3];
    const int*   offs_x  = (const int*)d_in[4];
    float* out = (float*)d_out;

    const int grid = CUTN * BLOCKS_PER_CUT;   // 12544 blocks of 256
    make_cutouts_kernel<<<grid, 256, 0, stream>>>(img, sizes_y, sizes_x,
                                                  offs_y, offs_x, out);
}

// Round 5
// 76.624 us; speedup vs baseline: 3.0758x; 3.0758x over previous
//
#include <hip/hip_runtime.h>

#define CUTN 128
#define CUT_SIZE 224
#define IMG_H 1024
#define IMG_W 1024
#define PAD 256          // IMG_H / 4
#define SIDE 1536        // IMG_H + 2*PAD
#define PX_PER_CUT (CUT_SIZE * CUT_SIZE)       // 50176
#define BLOCKS_PER_CUT (PX_PER_CUT / 256)      // 196

// d_ws layout: [0..127] u64 mlo | [128..255] u64 mhi | then 128 x int canon
struct DedupeWS {
    unsigned long long mlo[CUTN];
    unsigned long long mhi[CUTN];
    int canon[CUTN];
};

// Tiny kernel: thread t computes canonical owner of cut t and, if canonical,
// the bitmask of all cuts with identical params. O(128) work total per thread,
// 1 block — negligible.
__global__ __launch_bounds__(CUTN) void dedupe_kernel(
    const int* __restrict__ sizes_y, const int* __restrict__ sizes_x,
    const int* __restrict__ offs_y,  const int* __restrict__ offs_x,
    DedupeWS* __restrict__ ws)
{
    const int t = threadIdx.x;
    const int sy = sizes_y[t], sx = sizes_x[t];
    const int oy = offs_y[t],  ox = offs_x[t];

    int c = t;
    for (int d = 0; d < t; ++d) {
        if (sizes_y[d] == sy && sizes_x[d] == sx &&
            offs_y[d] == oy && offs_x[d] == ox) { c = d; break; }
    }
    ws->canon[t] = c;

    unsigned long long lo = 0ull, hi = 0ull;
    if (c == t) {
        for (int d = t; d < CUTN; ++d) {
            if (sizes_y[d] == sy && sizes_x[d] == sx &&
                offs_y[d] == oy && offs_x[d] == ox) {
                if (d < 64) lo |= 1ull << d;
                else        hi |= 1ull << (d - 64);
            }
        }
    }
    ws->mlo[t] = lo;
    ws->mhi[t] = hi;
}

// Main kernel: exact round-2 gather structure (46 us), plus O(1) dedupe check.
__global__ __launch_bounds__(256) void make_cutouts_kernel(
    const float* __restrict__ img,      // (3, 1024, 1024)
    const int* __restrict__ sizes_y,
    const int* __restrict__ sizes_x,
    const int* __restrict__ offs_y,
    const int* __restrict__ offs_x,
    const DedupeWS* __restrict__ ws,
    float* __restrict__ out)            // (128, 3, 224, 224)
{
    const int bid = blockIdx.x;
    const int cut = bid / BLOCKS_PER_CUT;            // uniform per block
    if (ws->canon[cut] != cut) return;               // duplicate: owner writes us

    const int rem = (bid - cut * BLOCKS_PER_CUT) * 256 + threadIdx.x;
    const int y   = rem / CUT_SIZE;
    const int x   = rem - y * CUT_SIZE;

    const float syf = (float)sizes_y[cut];
    const float sxf = (float)sizes_x[cut];
    const float oyf = (float)offs_y[cut];
    const float oxf = (float)offs_x[cut];

    const float gy = ((float)y + 0.5f) / (float)CUT_SIZE;
    const float gx = ((float)x + 0.5f) / (float)CUT_SIZE;

    const float ys = fminf(fmaxf(oyf + gy * syf - 0.5f, 0.0f), (float)(SIDE - 1));
    const float xs = fminf(fmaxf(oxf + gx * sxf - 0.5f, 0.0f), (float)(SIDE - 1));

    const int y0 = (int)floorf(ys);
    const int x0 = (int)floorf(xs);
    const float wy = ys - (float)y0;
    const float wx = xs - (float)x0;

    const int yy0 = y0 - PAD, yy1 = min(y0 + 1, SIDE - 1) - PAD;
    const int xx0 = x0 - PAD, xx1 = min(x0 + 1, SIDE - 1) - PAD;
    const bool vy0 = (unsigned)yy0 < (unsigned)IMG_H;
    const bool vy1 = (unsigned)yy1 < (unsigned)IMG_H;
    const bool vx0 = (unsigned)xx0 < (unsigned)IMG_W;
    const bool vx1 = (unsigned)xx1 < (unsigned)IMG_W;
    const bool vpair = vx0 && vx1;                   // xx0 in [0,1022]

    const float w00 = (1.0f - wy) * (1.0f - wx);
    const float w01 = (1.0f - wy) * wx;
    const float w10 = wy * (1.0f - wx);
    const float w11 = wy * wx;

    const long r0 = (long)yy0 * IMG_W;
    const long r1 = (long)yy1 * IMG_W;

    float vout[3];
    #pragma unroll
    for (int c = 0; c < 3; ++c) {
        const float* plane = img + (size_t)c * (IMG_H * IMG_W);

        float p00 = 0.0f, p01 = 0.0f, p10 = 0.0f, p11 = 0.0f;
        if (vy0) {
            if (vpair) {
                float2 t; __builtin_memcpy(&t, plane + r0 + xx0, 8);
                p00 = t.x; p01 = t.y;
            } else if (vx0) {
                p00 = plane[r0 + xx0];
            } else if (vx1) {
                p01 = plane[r0 + xx1];
            }
        }
        if (vy1) {
            if (vpair) {
                float2 t; __builtin_memcpy(&t, plane + r1 + xx0, 8);
                p10 = t.x; p11 = t.y;
            } else if (vx0) {
                p10 = plane[r1 + xx0];
            } else if (vx1) {
                p11 = plane[r1 + xx1];
            }
        }
        vout[c] = p00 * w00 + p01 * w01 + p10 * w10 + p11 * w11;
    }

    // Write own cutout and all duplicates (mask is uniform; 1 bit typical).
    unsigned long long lo = ws->mlo[cut], hi = ws->mhi[cut];
    const size_t pix = (size_t)y * CUT_SIZE + x;
    while (lo) {
        const int d = __ffsll(lo) - 1; lo &= lo - 1;
        #pragma unroll
        for (int c = 0; c < 3; ++c)
            __builtin_nontemporal_store(
                vout[c], &out[((size_t)d * 3 + c) * PX_PER_CUT + pix]);
    }
    while (hi) {
        const int d = __ffsll(hi) + 63; hi &= hi - 1;
        #pragma unroll
        for (int c = 0; c < 3; ++c)
            __builtin_nontemporal_store(
                vout[c], &out[((size_t)d * 3 + c) * PX_PER_CUT + pix]);
    }
}

extern "C" void kernel_launch(void* const* d_in, const int* in_sizes, int n_in,
                              void* d_out, int out_size, void* d_ws, size_t ws_size,
                              hipStream_t stream) {
    const float* img     = (const float*)d_in[0];
    const int*   sizes_y = (const int*)d_in[1];
    const int*   sizes_x = (const int*)d_in[2];
    const int*   offs_y  = (const int*)d_in[3];
    const int*   offs_x  = (const int*)d_in[4];
    float* out = (float*)d_out;
    DedupeWS* ws = (DedupeWS*)d_ws;   // 2560 B used

    dedupe_kernel<<<1, CUTN, 0, stream>>>(sizes_y, sizes_x, offs_y, offs_x, ws);

    const int grid = CUTN * BLOCKS_PER_CUT;   // 25088 blocks of 256
    make_cutouts_kernel<<<grid, 256, 0, stream>>>(img, sizes_y, sizes_x,
                                                  offs_y, offs_x, ws, out);
}

// Round 6
// 43.747 us; speedup vs baseline: 5.3873x; 1.7515x over previous
//
#include <hip/hip_runtime.h>

#define CUTN 128
#define CUT_SIZE 224
#define IMG_H 1024
#define IMG_W 1024
#define PAD 256          // IMG_H / 4
#define SIDE 1536        // IMG_H + 2*PAD
#define PX_PER_CUT (CUT_SIZE * CUT_SIZE)       // 50176
#define BLOCKS_PER_CUT (PX_PER_CUT / 256)      // 196

// Round-2 gather structure + in-kernel wave-ballot dedupe (O(1) per block).
__global__ __launch_bounds__(256) void make_cutouts_kernel(
    const float* __restrict__ img,      // (3, 1024, 1024)
    const int* __restrict__ sizes_y,
    const int* __restrict__ sizes_x,
    const int* __restrict__ offs_y,
    const int* __restrict__ offs_x,
    float* __restrict__ out)            // (128, 3, 224, 224)
{
    const int bid = blockIdx.x;
    const int cut = bid / BLOCKS_PER_CUT;            // uniform per block
    const int lane = (int)(threadIdx.x & 63);

    // own params (block-uniform)
    const int sy = sizes_y[cut], sx = sizes_x[cut];
    const int oy = offs_y[cut],  ox = offs_x[cut];

    // ---- ballot dedupe: lane l checks cuts l and l+64 ----
    const bool eq_lo = (sizes_y[lane]      == sy) & (sizes_x[lane]      == sx) &
                       (offs_y[lane]       == oy) & (offs_x[lane]       == ox);
    const bool eq_hi = (sizes_y[lane + 64] == sy) & (sizes_x[lane + 64] == sx) &
                       (offs_y[lane + 64]  == oy) & (offs_x[lane + 64]  == ox);
    const unsigned long long mlo = __ballot(eq_lo);
    const unsigned long long mhi = __ballot(eq_hi);
    const int canon = mlo ? (__ffsll(mlo) - 1) : (__ffsll(mhi) + 63);
    if (canon != cut) return;            // an earlier identical cutout owns this

    const int rem = (bid - cut * BLOCKS_PER_CUT) * 256 + (int)threadIdx.x;
    const int y   = rem / CUT_SIZE;
    const int x   = rem - y * CUT_SIZE;

    const float syf = (float)sy, sxf = (float)sx;
    const float oyf = (float)oy, oxf = (float)ox;

    const float gy = ((float)y + 0.5f) / (float)CUT_SIZE;
    const float gx = ((float)x + 0.5f) / (float)CUT_SIZE;

    const float ys = fminf(fmaxf(oyf + gy * syf - 0.5f, 0.0f), (float)(SIDE - 1));
    const float xs = fminf(fmaxf(oxf + gx * sxf - 0.5f, 0.0f), (float)(SIDE - 1));

    const int y0 = (int)floorf(ys);
    const int x0 = (int)floorf(xs);
    const float wy = ys - (float)y0;
    const float wx = xs - (float)x0;

    const int yy0 = y0 - PAD, yy1 = min(y0 + 1, SIDE - 1) - PAD;
    const int xx0 = x0 - PAD, xx1 = min(x0 + 1, SIDE - 1) - PAD;
    const bool vy0 = (unsigned)yy0 < (unsigned)IMG_H;
    const bool vy1 = (unsigned)yy1 < (unsigned)IMG_H;
    const bool vx0 = (unsigned)xx0 < (unsigned)IMG_W;
    const bool vx1 = (unsigned)xx1 < (unsigned)IMG_W;
    const bool vpair = vx0 && vx1;                   // xx0 in [0,1022]

    const float w00 = (1.0f - wy) * (1.0f - wx);
    const float w01 = (1.0f - wy) * wx;
    const float w10 = wy * (1.0f - wx);
    const float w11 = wy * wx;

    const long r0 = (long)yy0 * IMG_W;
    const long r1 = (long)yy1 * IMG_W;

    float vout[3];
    #pragma unroll
    for (int c = 0; c < 3; ++c) {
        const float* plane = img + (size_t)c * (IMG_H * IMG_W);

        float p00 = 0.0f, p01 = 0.0f, p10 = 0.0f, p11 = 0.0f;
        if (vy0) {
            if (vpair) {
                float2 t; __builtin_memcpy(&t, plane + r0 + xx0, 8);
                p00 = t.x; p01 = t.y;
            } else if (vx0) {
                p00 = plane[r0 + xx0];
            } else if (vx1) {
                p01 = plane[r0 + xx1];
            }
        }
        if (vy1) {
            if (vpair) {
                float2 t; __builtin_memcpy(&t, plane + r1 + xx0, 8);
                p10 = t.x; p11 = t.y;
            } else if (vx0) {
                p10 = plane[r1 + xx0];
            } else if (vx1) {
                p11 = plane[r1 + xx1];
            }
        }
        vout[c] = p00 * w00 + p01 * w01 + p10 * w10 + p11 * w11;
    }

    // ---- write own cutout and all duplicates (mask uniform per block) ----
    const size_t pix = (size_t)y * CUT_SIZE + x;
    unsigned long long lo = mlo, hi = mhi;
    while (lo) {
        const int d = __ffsll(lo) - 1; lo &= lo - 1;
        #pragma unroll
        for (int c = 0; c < 3; ++c)
            __builtin_nontemporal_store(
                vout[c], &out[((size_t)d * 3 + c) * PX_PER_CUT + pix]);
    }
    while (hi) {
        const int d = __ffsll(hi) + 63; hi &= hi - 1;
        #pragma unroll
        for (int c = 0; c < 3; ++c)
            __builtin_nontemporal_store(
                vout[c], &out[((size_t)d * 3 + c) * PX_PER_CUT + pix]);
    }
}

extern "C" void kernel_launch(void* const* d_in, const int* in_sizes, int n_in,
                              void* d_out, int out_size, void* d_ws, size_t ws_size,
                              hipStream_t stream) {
    const float* img     = (const float*)d_in[0];
    const int*   sizes_y = (const int*)d_in[1];
    const int*   sizes_x = (const int*)d_in[2];
    const int*   offs_y  = (const int*)d_in[3];
    const int*   offs_x  = (const int*)d_in[4];
    float* out = (float*)d_out;

    const int grid = CUTN * BLOCKS_PER_CUT;   // 25088 blocks of 256
    make_cutouts_kernel<<<grid, 256, 0, stream>>>(img, sizes_y, sizes_x,
                                                  offs_y, offs_x, out);
}